// Round 7
// baseline (115.902 us; speedup 1.0000x reference)
//
#include <hip/hip_runtime.h>

#define HORIZON 10
#define NUM_REGIONS 64
#define BB 32
#define TT 12
#define NN 100000

typedef float f32x2 __attribute__((ext_vector_type(2)));
typedef float f32x4 __attribute__((ext_vector_type(4)));

// Phase 1: pure-read time-mean of feature 0 -> means[b][n] (nt store),
// plus per-region sums via LDS -> global atomics.
__global__ __launch_bounds__(256) void reduce_kernel(
    const float* __restrict__ x, const int* __restrict__ cid,
    float* __restrict__ means, float* __restrict__ gsum)
{
    __shared__ float lsum[NUM_REGIONS];
    const int tid = threadIdx.x;
    if (tid < NUM_REGIONS) lsum[tid] = 0.0f;
    __syncthreads();

    const int b = blockIdx.y;
    const int i = blockIdx.x * 256 + tid;   // pair index: nodes 2i, 2i+1
    const int n0 = 2 * i;
    if (n0 < NN) {
        float s0 = 0.0f, s1 = 0.0f;
        #pragma unroll
        for (int t = 0; t < TT; ++t) {
            const f32x4 v = __builtin_nontemporal_load(
                reinterpret_cast<const f32x4*>(
                    x + ((size_t)(b * TT + t) * NN + n0) * 2));
            s0 += v.x;   // feature 0, node n0
            s1 += v.z;   // feature 0, node n0+1
        }
        const float m0 = s0 * (1.0f / 12.0f);
        const float m1 = s1 * (1.0f / 12.0f);
        f32x2 mv; mv.x = m0; mv.y = m1;
        __builtin_nontemporal_store(
            mv, reinterpret_cast<f32x2*>(means + (size_t)b * NN + n0));
        atomicAdd(&lsum[cid[n0]], m0);
        atomicAdd(&lsum[cid[n0 + 1]], m1);
    }
    __syncthreads();
    if (tid < NUM_REGIONS) {
        atomicAdd(&gsum[b * NUM_REGIONS + tid], lsum[tid]);
    }
}

// Phase 2: broadcast means over horizon. Plain loads (L2/L3-cached, 10x reuse),
// nontemporal float4 stores (no write-allocate).
__global__ __launch_bounds__(256) void broadcast_kernel(
    const float* __restrict__ means, float* __restrict__ out0)
{
    const int NQ = NN / 4;                            // 25000 float4 per (b,h)
    const int idx = blockIdx.x * 256 + threadIdx.x;   // 0 .. B*H*NQ-1
    const int q  = idx % NQ;
    const int bh = idx / NQ;                          // b*HORIZON + h
    const int b  = bh / HORIZON;
    const f32x4 v = *reinterpret_cast<const f32x4*>(
        means + (size_t)b * NN + 4 * q);
    __builtin_nontemporal_store(
        v, reinterpret_cast<f32x4*>(out0 + (size_t)idx * 4));
}

// Region counts.
__global__ __launch_bounds__(256) void count_kernel(
    const int* __restrict__ cid, float* __restrict__ gcount)
{
    __shared__ float lc[NUM_REGIONS];
    const int tid = threadIdx.x;
    if (tid < NUM_REGIONS) lc[tid] = 0.0f;
    __syncthreads();
    const int n = blockIdx.x * 256 + tid;
    if (n < NN) atomicAdd(&lc[cid[n]], 1.0f);
    __syncthreads();
    if (tid < NUM_REGIONS) atomicAdd(&gcount[tid], lc[tid]);
}

// Regional means broadcast over horizon.
__global__ __launch_bounds__(256) void finalize_kernel(
    const float* __restrict__ gsum, const float* __restrict__ gcount,
    float* __restrict__ out1)
{
    const int idx = blockIdx.x * 256 + threadIdx.x;  // 0 .. B*R-1
    if (idx >= BB * NUM_REGIONS) return;
    const int b = idx >> 6;
    const int r = idx & 63;
    const float v = gsum[idx] / gcount[r];
    const size_t base = (size_t)b * HORIZON * NUM_REGIONS + r;
    #pragma unroll
    for (int h = 0; h < HORIZON; ++h) {
        out1[base + (size_t)h * NUM_REGIONS] = v;
    }
}

extern "C" void kernel_launch(void* const* d_in, const int* in_sizes, int n_in,
                              void* d_out, int out_size, void* d_ws, size_t ws_size,
                              hipStream_t stream) {
    const float* x   = (const float*)d_in[0];
    const int*   cid = (const int*)d_in[1];
    float* out0 = (float*)d_out;
    float* out1 = out0 + (size_t)BB * HORIZON * NN;

    float* means  = (float*)d_ws;                    // BB*NN floats (12.8 MB)
    float* gsum   = means + (size_t)BB * NN;         // BB*NUM_REGIONS floats
    float* gcount = gsum + BB * NUM_REGIONS;         // NUM_REGIONS floats

    (void)hipMemsetAsync(gsum, 0,
                   (BB * NUM_REGIONS + NUM_REGIONS) * sizeof(float), stream);

    count_kernel<<<(NN + 255) / 256, 256, 0, stream>>>(cid, gcount);

    dim3 gridR((NN / 2 + 255) / 256, BB);            // (196, 32)
    reduce_kernel<<<gridR, 256, 0, stream>>>(x, cid, means, gsum);

    const int nq4 = BB * HORIZON * (NN / 4);         // 8,000,000 (divisible by 256)
    broadcast_kernel<<<nq4 / 256, 256, 0, stream>>>(means, out0);

    finalize_kernel<<<(BB * NUM_REGIONS + 255) / 256, 256, 0, stream>>>(
        gsum, gcount, out1);
}

// Round 8
// 92.913 us; speedup vs baseline: 1.2474x; 1.2474x over previous
//
#include <hip/hip_runtime.h>

#define HORIZON 10
#define NUM_REGIONS 64
#define BB 32
#define TT 12
#define NN 100000

typedef float f32x2 __attribute__((ext_vector_type(2)));
typedef float f32x4 __attribute__((ext_vector_type(4)));

// Fused kernel: plain (cached) x loads, nontemporal out0 stores.
// Per (b, node-pair): time-mean of feature 0, 10 horizon copies,
// LDS->global region sums.
__global__ __launch_bounds__(256) void mean_kernel(
    const float* __restrict__ x, const int* __restrict__ cid,
    float* __restrict__ out0, float* __restrict__ gsum)
{
    __shared__ float lsum[NUM_REGIONS];
    const int tid = threadIdx.x;
    if (tid < NUM_REGIONS) lsum[tid] = 0.0f;
    __syncthreads();

    const int b = blockIdx.y;
    const int i = blockIdx.x * 256 + tid;   // pair index: nodes 2i, 2i+1
    const int n0 = 2 * i;
    if (n0 < NN) {
        float s0 = 0.0f, s1 = 0.0f;
        #pragma unroll
        for (int t = 0; t < TT; ++t) {
            const f32x4 v = *reinterpret_cast<const f32x4*>(
                x + ((size_t)(b * TT + t) * NN + n0) * 2);
            s0 += v.x;   // feature 0, node n0
            s1 += v.z;   // feature 0, node n0+1
        }
        const float m0 = s0 * (1.0f / 12.0f);
        const float m1 = s1 * (1.0f / 12.0f);
        f32x2 mv; mv.x = m0; mv.y = m1;
        const size_t obase = (size_t)b * HORIZON * NN + n0;
        #pragma unroll
        for (int h = 0; h < HORIZON; ++h) {
            __builtin_nontemporal_store(
                mv, reinterpret_cast<f32x2*>(out0 + obase + (size_t)h * NN));
        }
        atomicAdd(&lsum[cid[n0]], m0);
        atomicAdd(&lsum[cid[n0 + 1]], m1);
    }
    __syncthreads();
    if (tid < NUM_REGIONS) {
        atomicAdd(&gsum[b * NUM_REGIONS + tid], lsum[tid]);
    }
}

// Region counts.
__global__ __launch_bounds__(256) void count_kernel(
    const int* __restrict__ cid, float* __restrict__ gcount)
{
    __shared__ float lc[NUM_REGIONS];
    const int tid = threadIdx.x;
    if (tid < NUM_REGIONS) lc[tid] = 0.0f;
    __syncthreads();
    const int n = blockIdx.x * 256 + tid;
    if (n < NN) atomicAdd(&lc[cid[n]], 1.0f);
    __syncthreads();
    if (tid < NUM_REGIONS) atomicAdd(&gcount[tid], lc[tid]);
}

// Regional means broadcast over horizon.
__global__ __launch_bounds__(256) void finalize_kernel(
    const float* __restrict__ gsum, const float* __restrict__ gcount,
    float* __restrict__ out1)
{
    const int idx = blockIdx.x * 256 + threadIdx.x;  // 0 .. B*R-1
    if (idx >= BB * NUM_REGIONS) return;
    const int b = idx >> 6;
    const int r = idx & 63;
    const float v = gsum[idx] / gcount[r];
    const size_t base = (size_t)b * HORIZON * NUM_REGIONS + r;
    #pragma unroll
    for (int h = 0; h < HORIZON; ++h) {
        out1[base + (size_t)h * NUM_REGIONS] = v;
    }
}

extern "C" void kernel_launch(void* const* d_in, const int* in_sizes, int n_in,
                              void* d_out, int out_size, void* d_ws, size_t ws_size,
                              hipStream_t stream) {
    const float* x   = (const float*)d_in[0];
    const int*   cid = (const int*)d_in[1];
    float* out0 = (float*)d_out;
    float* out1 = out0 + (size_t)BB * HORIZON * NN;

    float* gsum   = (float*)d_ws;                 // BB*NUM_REGIONS floats
    float* gcount = gsum + BB * NUM_REGIONS;      // NUM_REGIONS floats

    (void)hipMemsetAsync(d_ws, 0,
                   (BB * NUM_REGIONS + NUM_REGIONS) * sizeof(float), stream);

    dim3 gridA((NN / 2 + 255) / 256, BB);         // (196, 32)
    mean_kernel<<<gridA, 256, 0, stream>>>(x, cid, out0, gsum);

    count_kernel<<<(NN + 255) / 256, 256, 0, stream>>>(cid, gcount);

    finalize_kernel<<<(BB * NUM_REGIONS + 255) / 256, 256, 0, stream>>>(
        gsum, gcount, out1);
}

// Round 9
// 82.251 us; speedup vs baseline: 1.4091x; 1.1296x over previous
//
#include <hip/hip_runtime.h>

#define HORIZON 10
#define NUM_REGIONS 64
#define BB 32
#define TT 12
#define NN 100000

typedef float f32x2 __attribute__((ext_vector_type(2)));
typedef float f32x4 __attribute__((ext_vector_type(4)));

// Fused kernel: plain (cached) x loads, nontemporal out0 stores.
// Per (b, node-pair): time-mean of feature 0, 10 horizon copies,
// LDS->global region sums. Blocks with b==0 additionally accumulate
// the region counts (gcount).
__global__ __launch_bounds__(256) void mean_kernel(
    const float* __restrict__ x, const int* __restrict__ cid,
    float* __restrict__ out0, float* __restrict__ gsum,
    float* __restrict__ gcount)
{
    __shared__ float lsum[NUM_REGIONS];
    __shared__ float lcnt[NUM_REGIONS];
    const int tid = threadIdx.x;
    const int b = blockIdx.y;
    if (tid < NUM_REGIONS) {
        lsum[tid] = 0.0f;
        if (b == 0) lcnt[tid] = 0.0f;
    }
    __syncthreads();

    const int i = blockIdx.x * 256 + tid;   // pair index: nodes 2i, 2i+1
    const int n0 = 2 * i;
    if (n0 < NN) {
        float s0 = 0.0f, s1 = 0.0f;
        #pragma unroll
        for (int t = 0; t < TT; ++t) {
            const f32x4 v = *reinterpret_cast<const f32x4*>(
                x + ((size_t)(b * TT + t) * NN + n0) * 2);
            s0 += v.x;   // feature 0, node n0
            s1 += v.z;   // feature 0, node n0+1
        }
        const float m0 = s0 * (1.0f / 12.0f);
        const float m1 = s1 * (1.0f / 12.0f);
        f32x2 mv; mv.x = m0; mv.y = m1;
        const size_t obase = (size_t)b * HORIZON * NN + n0;
        #pragma unroll
        for (int h = 0; h < HORIZON; ++h) {
            __builtin_nontemporal_store(
                mv, reinterpret_cast<f32x2*>(out0 + obase + (size_t)h * NN));
        }
        const int c0 = cid[n0];
        const int c1 = cid[n0 + 1];
        atomicAdd(&lsum[c0], m0);
        atomicAdd(&lsum[c1], m1);
        if (b == 0) {
            atomicAdd(&lcnt[c0], 1.0f);
            atomicAdd(&lcnt[c1], 1.0f);
        }
    }
    __syncthreads();
    if (tid < NUM_REGIONS) {
        atomicAdd(&gsum[b * NUM_REGIONS + tid], lsum[tid]);
        if (b == 0) atomicAdd(&gcount[tid], lcnt[tid]);
    }
}

// Regional means broadcast over horizon.
__global__ __launch_bounds__(256) void finalize_kernel(
    const float* __restrict__ gsum, const float* __restrict__ gcount,
    float* __restrict__ out1)
{
    const int idx = blockIdx.x * 256 + threadIdx.x;  // 0 .. B*R-1
    if (idx >= BB * NUM_REGIONS) return;
    const int b = idx >> 6;
    const int r = idx & 63;
    const float v = gsum[idx] / gcount[r];
    const size_t base = (size_t)b * HORIZON * NUM_REGIONS + r;
    #pragma unroll
    for (int h = 0; h < HORIZON; ++h) {
        out1[base + (size_t)h * NUM_REGIONS] = v;
    }
}

extern "C" void kernel_launch(void* const* d_in, const int* in_sizes, int n_in,
                              void* d_out, int out_size, void* d_ws, size_t ws_size,
                              hipStream_t stream) {
    const float* x   = (const float*)d_in[0];
    const int*   cid = (const int*)d_in[1];
    float* out0 = (float*)d_out;
    float* out1 = out0 + (size_t)BB * HORIZON * NN;

    float* gsum   = (float*)d_ws;                 // BB*NUM_REGIONS floats
    float* gcount = gsum + BB * NUM_REGIONS;      // NUM_REGIONS floats

    (void)hipMemsetAsync(d_ws, 0,
                   (BB * NUM_REGIONS + NUM_REGIONS) * sizeof(float), stream);

    dim3 gridA((NN / 2 + 255) / 256, BB);         // (196, 32)
    mean_kernel<<<gridA, 256, 0, stream>>>(x, cid, out0, gsum, gcount);

    finalize_kernel<<<(BB * NUM_REGIONS + 255) / 256, 256, 0, stream>>>(
        gsum, gcount, out1);
}